// Round 4
// baseline (124.261 us; speedup 1.0000x reference)
//
#include <hip/hip_runtime.h>
#include <hip/hip_bf16.h>

// RBF kernel layer: out[n][m] = exp(-||x_n - c_m||^2)
// N=16384, M=4096, D=512, fp32 in/out.
// Round 4: PERSISTENT 256x256 8-phase GEMM. Grid = 256 blocks (1/CU); each
// block keeps its 256-row x-panel and sweeps 4 consecutive c-blocks with ONE
// continuous staging pipeline (32 K-tiles), paying one prologue instead of
// four and overlapping each output tile's store drain with the next tile's
// K-loop. T2 both-sides LDS swizzle, T4 counted vmcnt, T5 setprio.

#define NN 16384
#define MM 4096
#define DD 512
#define NU 32  // 4 output tiles x 8 K-tiles of BK=64

typedef __bf16 bf16x8 __attribute__((ext_vector_type(8)));
typedef float f32x4 __attribute__((ext_vector_type(4)));

__device__ __forceinline__ void async16(const void* g, void* l) {
  __builtin_amdgcn_global_load_lds(
      (const __attribute__((address_space(1))) void*)g,
      (__attribute__((address_space(3))) void*)l, 16, 0, 0);
}

#define MFMA(a, b, c) __builtin_amdgcn_mfma_f32_16x16x32_bf16(a, b, c, 0, 0, 0)

// ---------------------------------------------------------------------------
// Prep (merged x+c): fp32 row -> bf16 + fp32 squared norm. One wave per row.
// ---------------------------------------------------------------------------
__global__ __launch_bounds__(256) void prep_bf16(
    const float* __restrict__ x, const float* __restrict__ c,
    __bf16* __restrict__ xh, __bf16* __restrict__ ch,
    float* __restrict__ xsq, float* __restrict__ csq) {
  const int w = threadIdx.x >> 6;
  const int lane = threadIdx.x & 63;
  int row = blockIdx.x * 4 + w;
  const float* src = x;
  __bf16* dst = xh;
  float* sq = xsq;
  if (row >= NN) {
    row -= NN;
    src = c; dst = ch; sq = csq;
    if (row >= MM) return;
  }
  const float* p = src + (size_t)row * DD + lane * 8;
  float4 v0 = *(const float4*)p;
  float4 v1 = *(const float4*)(p + 4);
  float vv[8] = {v0.x, v0.y, v0.z, v0.w, v1.x, v1.y, v1.z, v1.w};
  float s = 0.f;
  bf16x8 h;
#pragma unroll
  for (int j = 0; j < 8; ++j) {
    s += vv[j] * vv[j];
    h[j] = (__bf16)vv[j];
  }
  *(bf16x8*)(dst + (size_t)row * DD + lane * 8) = h;
#pragma unroll
  for (int o = 32; o >= 1; o >>= 1) s += __shfl_down(s, o);
  if (lane == 0) sq[row] = s;
}

// ---------------------------------------------------------------------------
// Persistent 256x256 8-phase GEMM. 512 threads = 8 waves (2 x-row groups x
// 4 c-col groups); per wave 128 x-rows x 64 c-cols = 8x4 16x16 fragments.
// A-operand = centroid frag, B-operand = x frag (float4 epilogue stores).
//
// Block bid: XCD a = bid&7, p = bid>>3; x-panel = a*8 + p>>2 (8 panels/XCD,
// L2-resident); c-strip = p&3 -> c-blocks strip*4 + ot, ot = 0..3.
//
// Single K-tile counter u = 0..31 (ot = u>>3, kt = u&7). LDS double-buffer
// parity = u&1, continuous across ot boundaries. Staging schedule per tile u
// (each issue = 8KB = 512thr x 16B; X tile rows i*64..i*64+63 per issue i):
//   q0: X issues 1,3 of u+1   (rows 64-127/192-255: read in phases 2-3 of
//                              tile u-1 -> region free)
//   q1: C issues 0,1 of u+2   (buf u&1; C of tile u was read entirely in q0)
//   q2: C issues 2,3 of u+2
//   q3: X issues 0,2 of u+2   (rows 0-63/128-191: read in phases 0-1 of u)
// End-of-tile vmcnt(6): 8 issues outstanding, oldest 2 = u+1's X1,X3; all
// earlier pieces of u+1 are older in FIFO -> retired with them. u==30 ->
// vmcnt(0) (only u=31's X1,X3 outstanding); u==31 -> nothing staged.
// Epilogue stores (after u&7==7) enter the vmcnt FIFO; later counted waits
// become conservative (wait stores first) -- correct, small stall only.
// ---------------------------------------------------------------------------
__global__ __launch_bounds__(512, 2) void rbf_gemm(
    const __bf16* __restrict__ xh, const __bf16* __restrict__ ch,
    const float* __restrict__ xsq, const float* __restrict__ csq,
    float* __restrict__ out) {
  __shared__ __attribute__((aligned(16))) __bf16 sX[2][256 * 64];
  __shared__ __attribute__((aligned(16))) __bf16 sC[2][256 * 64];

  const int t = threadIdx.x;
  const int w = t >> 6;
  const int lane = t & 63;
  const int fr = lane & 15;
  const int fq = lane >> 4;
  const int wr = w >> 2;  // x-row half (0..1)
  const int wc = w & 3;   // c-col quarter (0..3)

  const int bid = blockIdx.x;
  const int a = bid & 7, p = bid >> 3;
  const int x0 = ((a << 3) + (p >> 2)) << 8;  // 64 x-panels
  const int strip = p & 3;                    // c-blocks strip*4 .. +3

  // --- staging addressing: wave w covers rows w*8..w*8+7 of each 64-row
  // issue; row&7 == lane>>3 -> 16B source slot XOR is wave-invariant ---
  const int srow = (w << 3) + (lane >> 3);
  const int kslot = ((lane & 7) ^ (lane >> 3)) << 3;  // bf16 elems
  const __bf16* gx = xh + (size_t)(x0 + srow) * DD + kslot;
  const __bf16* gc = ch + (size_t)((strip << 10) + srow) * DD + kslot;
  char* lXw = (char*)sX + (w << 10);
  char* lCw = (char*)sC + (w << 10);

#define STAGE_X(v, i) \
  async16(gx + (size_t)((i) * 64) * DD + ((v) & 7) * 64, \
          lXw + (((v) & 1) << 15) + (i) * 8192)
#define STAGE_C(v, i) \
  async16(gc + (size_t)((((v) >> 3) << 8) + (i) * 64) * DD + ((v) & 7) * 64, \
          lCw + (((v) & 1) << 15) + (i) * 8192)

  // --- ds_read addressing: byte = row*128 + ((ks*4+fq)^(row&7))*16 ---
  const int sx7 = fr & 7;
  const int sl0 = (fq ^ sx7) << 4;
  const int sl1 = ((4 | fq) ^ sx7) << 4;
  const int rowC = (wc * 64 + fr) * 128;
  const int rowX = (wr * 128 + fr) * 128;

  f32x4 acc[8][4];
#pragma unroll
  for (int m = 0; m < 8; ++m)
#pragma unroll
    for (int n = 0; n < 4; ++n) acc[m][n] = (f32x4){0.f, 0.f, 0.f, 0.f};

  // --- prologue: tile0 complete (8) + tile1 C0..3, X0, X2 (6) ---
  STAGE_C(0, 0); STAGE_C(0, 1); STAGE_C(0, 2); STAGE_C(0, 3);
  STAGE_X(0, 0); STAGE_X(0, 1); STAGE_X(0, 2); STAGE_X(0, 3);
  STAGE_C(1, 0); STAGE_C(1, 1); STAGE_C(1, 2); STAGE_C(1, 3);
  STAGE_X(1, 0); STAGE_X(1, 2);
  asm volatile("s_waitcnt vmcnt(6)" ::: "memory");
  __builtin_amdgcn_s_barrier();
  __builtin_amdgcn_sched_barrier(0);

#pragma unroll 1
  for (int u = 0; u < NU; ++u) {
    const int cur = u & 1;
    const char* bX = (const char*)sX + (cur << 15);
    const char* bC = (const char*)sC + (cur << 15);
    bf16x8 cf[4][2];
#pragma unroll
    for (int q = 0; q < 4; ++q) {
      if (q == 0) {
#pragma unroll
        for (int n = 0; n < 4; ++n) {
          cf[n][0] = *(const bf16x8*)(bC + rowC + n * 2048 + sl0);
          cf[n][1] = *(const bf16x8*)(bC + rowC + n * 2048 + sl1);
        }
      }
      bf16x8 xq[2][2];
#pragma unroll
      for (int mm = 0; mm < 2; ++mm) {
        xq[mm][0] = *(const bf16x8*)(bX + rowX + (2 * q + mm) * 2048 + sl0);
        xq[mm][1] = *(const bf16x8*)(bX + rowX + (2 * q + mm) * 2048 + sl1);
      }
      if (q == 0 && u + 1 < NU) { STAGE_X(u + 1, 1); STAGE_X(u + 1, 3); }
      if (q == 1 && u + 2 < NU) { STAGE_C(u + 2, 0); STAGE_C(u + 2, 1); }
      if (q == 2 && u + 2 < NU) { STAGE_C(u + 2, 2); STAGE_C(u + 2, 3); }
      if (q == 3 && u + 2 < NU) { STAGE_X(u + 2, 0); STAGE_X(u + 2, 2); }
      if (q == 0) asm volatile("s_waitcnt lgkmcnt(8)");
      __builtin_amdgcn_s_barrier();
      asm volatile("s_waitcnt lgkmcnt(0)" ::: "memory");
      __builtin_amdgcn_s_setprio(1);
#pragma unroll
      for (int mm = 0; mm < 2; ++mm)
#pragma unroll
        for (int n = 0; n < 4; ++n) {
          acc[2 * q + mm][n] = MFMA(cf[n][0], xq[mm][0], acc[2 * q + mm][n]);
          acc[2 * q + mm][n] = MFMA(cf[n][1], xq[mm][1], acc[2 * q + mm][n]);
        }
      __builtin_amdgcn_s_setprio(0);
      if (q == 3) {
        if (u < NU - 2)
          asm volatile("s_waitcnt vmcnt(6)" ::: "memory");
        else if (u == NU - 2)
          asm volatile("s_waitcnt vmcnt(0)" ::: "memory");
      }
      __builtin_amdgcn_s_barrier();
      if (q == 3) __builtin_amdgcn_sched_barrier(0);
    }

    if ((u & 7) == 7) {
      // --- per-output-tile epilogue: d = xsq + csq - 2*cross, exp, store.
      // C/D map: lane holds x-row fr, c-cols fq*4+reg [m89/m91] ---
      const int ot = u >> 3;
      const int cgb = (((strip << 2) + ot) << 8) + wc * 64 + (fq << 2);
      f32x4 csv[4];
#pragma unroll
      for (int n = 0; n < 4; ++n) csv[n] = *(const f32x4*)(csq + cgb + n * 16);
#pragma unroll
      for (int m = 0; m < 8; ++m) {
        const int xg = x0 + wr * 128 + m * 16 + fr;
        const float xs = xsq[xg];
        float* orow = out + (size_t)xg * MM + cgb;
#pragma unroll
        for (int n = 0; n < 4; ++n) {
          f32x4 v;
#pragma unroll
          for (int j = 0; j < 4; ++j) {
            float d = xs + csv[n][j] - 2.0f * acc[m][n][j];
            v[j] = __expf(-fmaxf(d, 0.0f));
            acc[m][n][j] = 0.0f;
          }
          *(f32x4*)(orow + n * 16) = v;
        }
      }
    }
  }
}

// ---------------------------------------------------------------------------
// Fallback (ws too small): direct tiled fp32 distance kernel.
// ---------------------------------------------------------------------------
__global__ void rbf_naive(const float* __restrict__ x,
                          const float* __restrict__ c,
                          float* __restrict__ out) {
  __shared__ float sx[16][17], sc[16][17];
  const int tx = threadIdx.x, ty = threadIdx.y;
  const int row = blockIdx.y * 16 + ty;
  const int colb = blockIdx.x * 16;
  float d = 0.f;
  for (int k0 = 0; k0 < DD; k0 += 16) {
    sx[ty][tx] = x[(size_t)row * DD + k0 + tx];
    sc[ty][tx] = c[(size_t)(colb + ty) * DD + k0 + tx];
    __syncthreads();
#pragma unroll
    for (int k = 0; k < 16; ++k) {
      float diff = sx[ty][k] - sc[tx][k];
      d += diff * diff;
    }
    __syncthreads();
  }
  out[(size_t)row * MM + colb + tx] = __expf(-d);
}

extern "C" void kernel_launch(void* const* d_in, const int* in_sizes, int n_in,
                              void* d_out, int out_size, void* d_ws,
                              size_t ws_size, hipStream_t stream) {
  const float* x = (const float*)d_in[0];
  const float* c = (const float*)d_in[1];
  float* out = (float*)d_out;

  char* ws = (char*)d_ws;
  __bf16* xh = (__bf16*)ws;
  __bf16* ch = xh + (size_t)NN * DD;
  float* xsq = (float*)(ch + (size_t)MM * DD);
  float* csq = xsq + NN;
  const size_t need = (size_t)((char*)(csq + MM) - ws);

  if (ws_size < need) {
    dim3 grid(MM / 16, NN / 16), block(16, 16);
    rbf_naive<<<grid, block, 0, stream>>>(x, c, out);
    return;
  }

  prep_bf16<<<(NN + MM) / 4, 256, 0, stream>>>(x, c, xh, ch, xsq, csq);
  rbf_gemm<<<256, 512, 0, stream>>>(xh, ch, xsq, csq, out);
}